// Round 8
// baseline (1617.120 us; speedup 1.0000x reference)
//
#include <hip/hip_runtime.h>
#include <math.h>

#define Bn   16
#define Nn   4096
#define Cn   64
#define Mn   1024
#define Kn   32
#define OUTn 128
#define EPS  1e-5f

typedef unsigned long long u64;
typedef unsigned int u32;

__device__ __forceinline__ u64 u64min(u64 a, u64 b) { return a < b ? a : b; }
__device__ __forceinline__ u64 u64max(u64 a, u64 b) { return a > b ? a : b; }

// DPP move of a u64 (2x i32 update_dpp). old = x -> invalid/masked lanes keep x,
// the identity for both max and min combines.
template<int CTRL>
__device__ __forceinline__ u64 dpp_u64(u64 x) {
  union { u64 q; u32 w[2]; } in, out;
  in.q = x;
  out.w[0] = (u32)__builtin_amdgcn_update_dpp((int)in.w[0], (int)in.w[0], CTRL, 0xf, 0xf, false);
  out.w[1] = (u32)__builtin_amdgcn_update_dpp((int)in.w[1], (int)in.w[1], CTRL, 0xf, 0xf, false);
  return out.q;
}

// Canonical GCN wave64 reduce: row_shr 1,2,4,8 -> bcast15 -> bcast31.
// Result valid in lane 63 only. Pure VALU.
__device__ __forceinline__ u64 wave_max_dpp(u64 v) {
  v = u64max(v, dpp_u64<0x111>(v));
  v = u64max(v, dpp_u64<0x112>(v));
  v = u64max(v, dpp_u64<0x114>(v));
  v = u64max(v, dpp_u64<0x118>(v));
  v = u64max(v, dpp_u64<0x142>(v));
  v = u64max(v, dpp_u64<0x143>(v));
  return v;
}
__device__ __forceinline__ u64 wave_min_dpp(u64 v) {
  v = u64min(v, dpp_u64<0x111>(v));
  v = u64min(v, dpp_u64<0x112>(v));
  v = u64min(v, dpp_u64<0x114>(v));
  v = u64min(v, dpp_u64<0x118>(v));
  v = u64min(v, dpp_u64<0x142>(v));
  v = u64min(v, dpp_u64<0x143>(v));
  return v;
}

// ---------------------------------------------------------------------------
// FPS: one block/batch, 256 threads, 16 pts/thread in regs.
// Packed keys: (bits(d)<<32)|~n ; u64 MAX == (max d, tie -> lowest n).
// Coords-through-LDS: each wave's OWNER lane (t == idx&255; knows its local
// slot j = idx>>8, uniform) writes {key, x,y,z} to the parity slot BEFORE the
// barrier. After the barrier every thread merges 4 (key,coord) pairs with
// cndmasks -- the dependent pts4[winner] LDS read is gone from the chain.
// Distance update keeps the reference difference form (bit-stable selection).
// ---------------------------------------------------------------------------
__global__ __launch_bounds__(256) void fps_kernel(
    const float* __restrict__ xyz, float* __restrict__ cent)
{
  __shared__ float4 pts4[Nn];          // 64 KB (init staging only)
  __shared__ __align__(16) u64    partk[2][4];
  __shared__ __align__(16) float4 partc[2][4];

  const int b = blockIdx.x;
  const int t = threadIdx.x;
  const int wid = t >> 6;
  const float* src = xyz + (size_t)b * Nn * 3;

  for (int i = t; i < Nn; i += 256) {
    pts4[i] = make_float4(src[3*i+0], src[3*i+1], src[3*i+2], 0.0f);
  }
  __syncthreads();

  const float4 c0 = pts4[0];

  float px[16], py[16], pz[16], d[16];
  u32 ninv[16];
#pragma unroll
  for (int j = 0; j < 16; ++j) {
    const int n = j * 256 + t;
    ninv[j] = (u32)(~n);
    const float4 p = pts4[n];
    px[j] = p.x; py[j] = p.y; pz[j] = p.z;
    const float dx = px[j] - c0.x, dy = py[j] - c0.y, dz = pz[j] - c0.z;
    d[j] = (dx * dx + dy * dy) + dz * dz;
  }

  if (t == 0) {
    float* o = cent + (size_t)b * Mn * 3;
    o[0] = c0.x; o[1] = c0.y; o[2] = c0.z;
  }

  for (int m = 1; m < Mn; ++m) {
    // pack + depth-4 tree max
    u64 k[16];
#pragma unroll
    for (int j = 0; j < 16; ++j)
      k[j] = ((u64)__float_as_uint(d[j]) << 32) | ninv[j];
#pragma unroll
    for (int st = 1; st < 16; st <<= 1)
#pragma unroll
      for (int j = 0; j < 16; j += (st << 1))
        k[j] = u64max(k[j], k[j + st]);

    const u64 wmax = wave_max_dpp(k[0]);            // valid in lane 63
    const u32 klo = (u32)__builtin_amdgcn_readlane((int)(u32)wmax, 63);
    const u32 khi = (u32)__builtin_amdgcn_readlane((int)(u32)(wmax >> 32), 63);
    const int idx  = (int)(~klo);                   // winning point index (uniform)
    const int par = m & 1;

    if (t == (idx & 255)) {                         // unique owner per wave
      const int jsel = idx >> 8;                    // uniform local slot
      float sx = px[0], sy = py[0], sz = pz[0];
#pragma unroll
      for (int j = 1; j < 16; ++j)
        if (jsel == j) { sx = px[j]; sy = py[j]; sz = pz[j]; }
      partk[par][wid] = ((u64)khi << 32) | klo;
      partc[par][wid] = make_float4(sx, sy, sz, 0.0f);
    }
    __syncthreads();

    // merge 4 (key, coords) pairs -- no dependent second LDS read
    u64 ka = partk[par][0]; float4 qa = partc[par][0];
    {
      const u64 kb = partk[par][1]; const float4 qb = partc[par][1];
      if (kb > ka) { ka = kb; qa = qb; }
    }
    {
      u64 kc = partk[par][2]; float4 qc = partc[par][2];
      const u64 kd = partk[par][3]; const float4 qd = partc[par][3];
      if (kd > kc) { kc = kd; qc = qd; }
      if (kc > ka) { ka = kc; qa = qc; }
    }
    const float4 cp = qa;

    if (t == 0) {
      float* o = cent + ((size_t)b * Mn + m) * 3;
      o[0] = cp.x; o[1] = cp.y; o[2] = cp.z;
    }

#pragma unroll
    for (int j = 0; j < 16; ++j) {
      const float dx = px[j] - cp.x, dy = py[j] - cp.y, dz = pz[j] - cp.z;
      const float nd = (dx * dx + dy * dy) + dz * dz;
      d[j] = fminf(d[j], nd);
    }
  }
}

// ---------------------------------------------------------------------------
// KNN: ONE WAVE per centroid (4 centroids/block), zero barriers, zero LDS.
// (unchanged -- ~120us, not the bottleneck)
// ---------------------------------------------------------------------------
__global__ __launch_bounds__(256) void knn_kernel(
    const float* __restrict__ xyz, const float* __restrict__ cent,
    int* __restrict__ osel)
{
  const int t    = threadIdx.x;
  const int lane = t & 63;
  const int wid  = __builtin_amdgcn_readfirstlane(t >> 6);
  const int g    = (blockIdx.x << 2) + wid;      // centroid id
  const int b    = g >> 10;
  const float* P = xyz + (size_t)b * Nn * 3;

  const float cx = cent[(size_t)g * 3 + 0];
  const float cy = cent[(size_t)g * 3 + 1];
  const float cz = cent[(size_t)g * 3 + 2];
  const float cc2 = (cx * cx + cy * cy) + cz * cz;

  u64 kk[4][16];
  u64 gm0, gm1, gm2, gm3;

#pragma unroll
  for (int grp = 0; grp < 4; ++grp) {
#pragma unroll
    for (int j = 0; j < 16; ++j) {
      const int n = grp * 1024 + j * 64 + lane;
      const float x = P[n*3+0], y = P[n*3+1], z = P[n*3+2];
      const float pp = (x * x + y * y) + z * z;
      const float dt = (cx * x + cy * y) + cz * z;
      const float d2 = (cc2 + pp) - 2.0f * dt;
      const u32 bu = __float_as_uint(d2);
      const u32 mo = bu ^ (0x80000000u | (u32)((int)bu >> 31)); // order-preserving
      kk[grp][j] = ((u64)mo << 32) | (u32)n;
    }
  }
#define TREE16(dst, A)                                                  \
  {                                                                     \
    u64 t0 = u64min(A[0], A[1]),  t1 = u64min(A[2], A[3]);              \
    u64 t2 = u64min(A[4], A[5]),  t3 = u64min(A[6], A[7]);              \
    u64 t4 = u64min(A[8], A[9]),  t5 = u64min(A[10], A[11]);            \
    u64 t6 = u64min(A[12], A[13]), t7 = u64min(A[14], A[15]);           \
    t0 = u64min(t0, t1); t2 = u64min(t2, t3);                           \
    t4 = u64min(t4, t5); t6 = u64min(t6, t7);                           \
    dst = u64min(u64min(t0, t2), u64min(t4, t6));                       \
  }
  TREE16(gm0, kk[0]); TREE16(gm1, kk[1]);
  TREE16(gm2, kk[2]); TREE16(gm3, kk[3]);
  u64 bk = u64min(u64min(gm0, gm1), u64min(gm2, gm3));

  int myfi = 0;
  for (int s = 0; s < Kn; ++s) {
    const u64 v = wave_min_dpp(bk);
    const u32 flo = (u32)__builtin_amdgcn_readlane((int)(u32)v, 63);
    const int fi = (int)flo;                       // point index (uniform)
    if (lane == s) myfi = fi;

    const int og = __builtin_amdgcn_readfirstlane(fi >> 10);       // group
    const int oj = __builtin_amdgcn_readfirstlane((fi >> 6) & 15); // slot
    if (lane == (fi & 63)) {                       // unique owner lane
#pragma unroll
      for (int grp = 0; grp < 4; ++grp) {
        if (grp == og) {
#pragma unroll
          for (int j = 0; j < 16; ++j)
            if (j == oj) kk[grp][j] = ~0ull;
          u64 nm;
          TREE16(nm, kk[grp]);
          if (grp == 0) gm0 = nm;
          else if (grp == 1) gm1 = nm;
          else if (grp == 2) gm2 = nm;
          else gm3 = nm;
        }
      }
      bk = u64min(u64min(gm0, gm1), u64min(gm2, gm3));
    }
  }
#undef TREE16

  if (lane < Kn) osel[(size_t)g * 128 + lane] = myfi;
}

// ---------------------------------------------------------------------------
// MLP: one block (256 thr) per 4 centroids = 128 rows.
// Restructured: row hoisted to 64 VGPRs per layer; cc-outer jammed x4 (four
// independent 64-deep FMA chains over CONTIGUOUS weight rows -> scheduler can
// overlap weight-load latency under a 256-FMA window). Layer 3 in two 32-col
// halves to cap VGPRs. LN via cross-wave LDS partial exchange (unchanged).
// ---------------------------------------------------------------------------
__global__ __launch_bounds__(256) void mlp_kernel(
    const float* __restrict__ xyz, const float* __restrict__ feat,
    const float* __restrict__ W1, const float* __restrict__ b1,
    const float* __restrict__ g1, const float* __restrict__ be1,
    const float* __restrict__ W2, const float* __restrict__ b2,
    const float* __restrict__ g2, const float* __restrict__ be2,
    const float* __restrict__ Wout, const float* __restrict__ bout,
    const float* __restrict__ cent, float* __restrict__ out)
{
  __shared__ float A[128][68];
  __shared__ float lnS[2][128];
  __shared__ float lnQ[2][128];

  const int bm0 = blockIdx.x << 2;
  const int b   = bm0 >> 10;
  const int t   = threadIdx.x;
  const int wid = __builtin_amdgcn_readfirstlane(t >> 6);
  const int lane = t & 63;

  const float* F = feat + (size_t)b * Nn * Cn;
  const float* P = xyz  + (size_t)b * Nn * 3;
  const int* osel = (const int*)out;

  // ---- gather: 2 threads per row ----
  {
    const int row = t >> 1, half = t & 1;
    const int g = bm0 + (row >> 5);
    const int n = osel[(size_t)g * 128 + (row & 31)];
    const float4* f4 = (const float4*)(F + (size_t)n * Cn + half * 32);
#pragma unroll
    for (int q = 0; q < 8; ++q)
      *(float4*)&A[row][half * 32 + q * 4] = f4[q];
    if (half) {
      A[row][64] = P[n*3+0] - cent[(size_t)g*3+0];
      A[row][65] = P[n*3+1] - cent[(size_t)g*3+1];
      A[row][66] = P[n*3+2] - cent[(size_t)g*3+2];
      A[row][67] = 0.0f;
    }
  }
  __syncthreads();

  const int row  = ((wid & 1) << 6) + lane;
  const int c0   = (wid >> 1) << 5;
  const int slot = wid >> 1;

  float x[64];
  float acc[32];

  // ---- load row to registers ----
#pragma unroll
  for (int i = 0; i < 16; ++i) {
    const float4 v = *(const float4*)&A[row][4 * i];
    x[4*i+0] = v.x; x[4*i+1] = v.y; x[4*i+2] = v.z; x[4*i+3] = v.w;
  }
  const float xc0 = A[row][64], xc1 = A[row][65], xc2 = A[row][66];

  // ---- layer 1 (K=67): X cols 0..63 -> W1 cols 3..66; coords -> W1 0..2 ----
#pragma unroll
  for (int c4 = 0; c4 < 8; ++c4) {
    const int cA = c0 + c4 * 4;
    const float* w0 = W1 + (size_t)(cA + 0) * 67;
    const float* w1 = W1 + (size_t)(cA + 1) * 67;
    const float* w2 = W1 + (size_t)(cA + 2) * 67;
    const float* w3 = W1 + (size_t)(cA + 3) * 67;
    float s0 = fmaf(xc2, w0[2], fmaf(xc1, w0[1], fmaf(xc0, w0[0], b1[cA + 0])));
    float s1 = fmaf(xc2, w1[2], fmaf(xc1, w1[1], fmaf(xc0, w1[0], b1[cA + 1])));
    float s2 = fmaf(xc2, w2[2], fmaf(xc1, w2[1], fmaf(xc0, w2[0], b1[cA + 2])));
    float s3 = fmaf(xc2, w3[2], fmaf(xc1, w3[1], fmaf(xc0, w3[0], b1[cA + 3])));
#pragma unroll
    for (int kq = 0; kq < 64; ++kq) {
      const float xv = x[kq];
      s0 = fmaf(xv, w0[3 + kq], s0);
      s1 = fmaf(xv, w1[3 + kq], s1);
      s2 = fmaf(xv, w2[3 + kq], s2);
      s3 = fmaf(xv, w3[3 + kq], s3);
    }
    acc[c4*4+0] = s0; acc[c4*4+1] = s1; acc[c4*4+2] = s2; acc[c4*4+3] = s3;
  }

  // ---- LN1 + ReLU -> A ----
  {
    float s = 0.0f, q = 0.0f;
#pragma unroll
    for (int cc = 0; cc < 32; ++cc) { s += acc[cc]; q = fmaf(acc[cc], acc[cc], q); }
    lnS[slot][row] = s; lnQ[slot][row] = q;
    __syncthreads();
    const float st = s + lnS[slot ^ 1][row];
    const float qt = q + lnQ[slot ^ 1][row];
    const float mu = st * 0.015625f;
    const float var = qt * 0.015625f - mu * mu;
    const float rs = rsqrtf(var + EPS);
#pragma unroll
    for (int cc = 0; cc < 32; ++cc) {
      const float y = (acc[cc] - mu) * rs * g1[c0 + cc] + be1[c0 + cc];
      acc[cc] = fmaxf(y, 0.0f);
    }
#pragma unroll
    for (int c4 = 0; c4 < 8; ++c4)
      *(float4*)&A[row][c0 + c4 * 4] =
          make_float4(acc[c4*4], acc[c4*4+1], acc[c4*4+2], acc[c4*4+3]);
  }
  __syncthreads();

  // ---- layer 2 (K=64) ----
#pragma unroll
  for (int i = 0; i < 16; ++i) {
    const float4 v = *(const float4*)&A[row][4 * i];
    x[4*i+0] = v.x; x[4*i+1] = v.y; x[4*i+2] = v.z; x[4*i+3] = v.w;
  }
#pragma unroll
  for (int c4 = 0; c4 < 8; ++c4) {
    const int cA = c0 + c4 * 4;
    const float* w0 = W2 + (size_t)(cA + 0) * 64;
    const float* w1 = W2 + (size_t)(cA + 1) * 64;
    const float* w2 = W2 + (size_t)(cA + 2) * 64;
    const float* w3 = W2 + (size_t)(cA + 3) * 64;
    float s0 = b2[cA + 0], s1 = b2[cA + 1], s2 = b2[cA + 2], s3 = b2[cA + 3];
#pragma unroll
    for (int kq = 0; kq < 64; ++kq) {
      const float xv = x[kq];
      s0 = fmaf(xv, w0[kq], s0);
      s1 = fmaf(xv, w1[kq], s1);
      s2 = fmaf(xv, w2[kq], s2);
      s3 = fmaf(xv, w3[kq], s3);
    }
    acc[c4*4+0] = s0; acc[c4*4+1] = s1; acc[c4*4+2] = s2; acc[c4*4+3] = s3;
  }

  // ---- LN2 + ReLU -> A ----
  {
    float s = 0.0f, q = 0.0f;
#pragma unroll
    for (int cc = 0; cc < 32; ++cc) { s += acc[cc]; q = fmaf(acc[cc], acc[cc], q); }
    lnS[slot][row] = s; lnQ[slot][row] = q;
    __syncthreads();
    const float st = s + lnS[slot ^ 1][row];
    const float qt = q + lnQ[slot ^ 1][row];
    const float mu = st * 0.015625f;
    const float var = qt * 0.015625f - mu * mu;
    const float rs = rsqrtf(var + EPS);
#pragma unroll
    for (int cc = 0; cc < 32; ++cc) {
      const float y = (acc[cc] - mu) * rs * g2[c0 + cc] + be2[c0 + cc];
      acc[cc] = fmaxf(y, 0.0f);
    }
#pragma unroll
    for (int c4 = 0; c4 < 8; ++c4)
      *(float4*)&A[row][c0 + c4 * 4] =
          make_float4(acc[c4*4], acc[c4*4+1], acc[c4*4+2], acc[c4*4+3]);
  }
  __syncthreads();

  // ---- layer 3 (K=64) in two 32-col halves + maxpool + store ----
#pragma unroll
  for (int i = 0; i < 16; ++i) {
    const float4 v = *(const float4*)&A[row][4 * i];
    x[4*i+0] = v.x; x[4*i+1] = v.y; x[4*i+2] = v.z; x[4*i+3] = v.w;
  }
  const int c03 = (wid >> 1) << 6;
  const int g   = bm0 + ((wid & 1) << 1) + (lane >> 5);
  float* og = out + (size_t)g * OUTn + c03;

#pragma unroll
  for (int h = 0; h < 2; ++h) {
    const int cb = c03 + h * 32;
#pragma unroll
    for (int c4 = 0; c4 < 8; ++c4) {
      const int cA = cb + c4 * 4;
      const float* w0 = Wout + (size_t)(cA + 0) * 64;
      const float* w1 = Wout + (size_t)(cA + 1) * 64;
      const float* w2 = Wout + (size_t)(cA + 2) * 64;
      const float* w3 = Wout + (size_t)(cA + 3) * 64;
      float s0 = bout[cA + 0], s1 = bout[cA + 1], s2 = bout[cA + 2], s3 = bout[cA + 3];
#pragma unroll
      for (int kq = 0; kq < 64; ++kq) {
        const float xv = x[kq];
        s0 = fmaf(xv, w0[kq], s0);
        s1 = fmaf(xv, w1[kq], s1);
        s2 = fmaf(xv, w2[kq], s2);
        s3 = fmaf(xv, w3[kq], s3);
      }
      acc[c4*4+0] = s0; acc[c4*4+1] = s1; acc[c4*4+2] = s2; acc[c4*4+3] = s3;
    }
    // pool over 32 rows (lanes within 32-lane half)
#pragma unroll
    for (int cc = 0; cc < 32; ++cc) {
      float v = acc[cc];
      v = fmaxf(v, __shfl_xor(v, 1));
      v = fmaxf(v, __shfl_xor(v, 2));
      v = fmaxf(v, __shfl_xor(v, 4));
      v = fmaxf(v, __shfl_xor(v, 8));
      v = fmaxf(v, __shfl_xor(v, 16));
      acc[cc] = v;
    }
#pragma unroll
    for (int cc = 0; cc < 32; ++cc)
      if ((lane & 31) == cc) og[h * 32 + cc] = acc[cc];
  }
}

// ---------------------------------------------------------------------------
extern "C" void kernel_launch(void* const* d_in, const int* in_sizes, int n_in,
                              void* d_out, int out_size, void* d_ws, size_t ws_size,
                              hipStream_t stream)
{
  const float* xyz  = (const float*)d_in[0];
  const float* feat = (const float*)d_in[1];
  const float* W1   = (const float*)d_in[2];
  const float* b1   = (const float*)d_in[3];
  const float* g1   = (const float*)d_in[4];
  const float* be1  = (const float*)d_in[5];
  const float* W2   = (const float*)d_in[6];
  const float* b2   = (const float*)d_in[7];
  const float* g2   = (const float*)d_in[8];
  const float* be2  = (const float*)d_in[9];
  const float* Wout = (const float*)d_in[10];
  const float* bout = (const float*)d_in[11];

  float* outp = (float*)d_out;
  float* cent = outp;                             // (B, M, 3)
  float* o    = outp + (size_t)Bn * Mn * 3;       // (B, M, 128)

  fps_kernel<<<Bn, 256, 0, stream>>>(xyz, cent);
  knn_kernel<<<Bn * Mn / 4, 256, 0, stream>>>(xyz, cent, (int*)o);
  mlp_kernel<<<Bn * Mn / 4, 256, 0, stream>>>(xyz, feat,
                                              W1, b1, g1, be1,
                                              W2, b2, g2, be2,
                                              Wout, bout, cent, o);
}